// Round 4
// baseline (12085.831 us; speedup 1.0000x reference)
//
#include <hip/hip_runtime.h>
#include <math.h>

// Problem constants
#define S_LEN 256
#define BATCH 64
#define WLEN  16
#define EC    64
#define HC    128
#define HWID  512
#define TT    32
#define DD    557
#define DDP   560    // padded leading dim for X / Wih copies (float4-aligned)
#define NSEQ  16384
#define NSB   16384
#define GC    512    // 4*HC
#define GW    2048   // 4*HWID
#define CHUNK 32
#define CROWS (CHUNK*BATCH)   // 2048

__device__ __forceinline__ float sigf(float x){ return 1.f/(1.f+__expf(-x)); }

// =================== fp32 GEMM: C = act(A(MxK)*B(NxK)^T + bias) =======================
// 128x128 tile, 8x8 micro, BK=16, 256 threads. REQUIRES lda%4==0, ldb%4==0, K%16==0,
// and A/B zero-padded out to K. M,N guarded.
#define BM 128
#define BN 128
#define BK 16
__global__ __launch_bounds__(256, 2)
void gemm128(const float* __restrict__ A, int lda,
             const float* __restrict__ Bm, int ldb,
             float* __restrict__ C, int ldc,
             int M, int N, int K,
             const float* __restrict__ bias, int act)
{
    __shared__ float As[BK][BM+4];
    __shared__ float Bs[BK][BN+4];
    const int tid = threadIdx.x;
    const int m0 = blockIdx.x * BM;
    const int n0 = blockIdx.y * BN;
    const int tr = tid >> 4;   // 0..15
    const int tc = tid & 15;   // 0..15
    float acc[8][8];
    #pragma unroll
    for (int i=0;i<8;i++)
        #pragma unroll
        for(int j=0;j<8;j++) acc[i][j]=0.f;

    for (int k0 = 0; k0 < K; k0 += BK) {
        #pragma unroll
        for (int i=0;i<2;i++){
            int e = i*256 + tid;
            int m = e >> 2, kq = e & 3;
            int gm = m0 + m;
            float4 v = make_float4(0.f,0.f,0.f,0.f);
            if (gm < M) v = *(const float4*)&A[(size_t)gm*lda + k0 + kq*4];
            As[kq*4+0][m]=v.x; As[kq*4+1][m]=v.y; As[kq*4+2][m]=v.z; As[kq*4+3][m]=v.w;
        }
        #pragma unroll
        for (int i=0;i<2;i++){
            int e = i*256 + tid;
            int n = e >> 2, kq = e & 3;
            int gn = n0 + n;
            float4 v = make_float4(0.f,0.f,0.f,0.f);
            if (gn < N) v = *(const float4*)&Bm[(size_t)gn*ldb + k0 + kq*4];
            Bs[kq*4+0][n]=v.x; Bs[kq*4+1][n]=v.y; Bs[kq*4+2][n]=v.z; Bs[kq*4+3][n]=v.w;
        }
        __syncthreads();
        #pragma unroll
        for (int k = 0; k < BK; k++) {
            float4 a0 = *(float4*)&As[k][tr*8];
            float4 a1 = *(float4*)&As[k][tr*8+4];
            float4 b0 = *(float4*)&Bs[k][tc*8];
            float4 b1 = *(float4*)&Bs[k][tc*8+4];
            float av[8] = {a0.x,a0.y,a0.z,a0.w,a1.x,a1.y,a1.z,a1.w};
            float bv[8] = {b0.x,b0.y,b0.z,b0.w,b1.x,b1.y,b1.z,b1.w};
            #pragma unroll
            for (int i=0;i<8;i++)
                #pragma unroll
                for (int j=0;j<8;j++)
                    acc[i][j] += av[i]*bv[j];
        }
        __syncthreads();
    }
    #pragma unroll
    for (int i=0;i<8;i++){
        int m = m0 + tr*8 + i;
        if (m >= M) continue;
        #pragma unroll
        for (int j=0;j<8;j++){
            int n = n0 + tc*8 + j;
            if (n >= N) continue;
            float v = acc[i][j];
            if (bias) v += bias[n];
            if (act==1) v = tanhf(v);
            C[(size_t)m*ldc + n] = v;
        }
    }
}

// ============ P[v][j] = char_emb(v,:) . Wih(j,:) + bih[j] + bhh[j], per dir ===========
__global__ void char_pmat(const float* __restrict__ ce,
                          const float* __restrict__ wf, const float* __restrict__ wb,
                          const float* __restrict__ bihF, const float* __restrict__ bhhF,
                          const float* __restrict__ bihB, const float* __restrict__ bhhB,
                          float* __restrict__ Pf, float* __restrict__ Pb)
{
    int gid = blockIdx.x*blockDim.x + threadIdx.x;
    if (gid >= 2*128*GC) return;
    int d = gid >> 16;
    int r = gid & 65535;
    int v = r >> 9, j = r & 511;
    const float* wW = d ? wb : wf;
    float s = 0.f;
    for (int e=0;e<EC;e++) s += ce[v*EC+e]*wW[j*EC+e];
    s += (d ? bihB[j]+bhhB[j] : bihF[j]+bhhF[j]);
    (d ? Pb : Pf)[r] = s;
}

__global__ void bias_sum(const float* __restrict__ a1, const float* __restrict__ a2,
                         const float* __restrict__ b1, const float* __restrict__ b2,
                         float* __restrict__ of, float* __restrict__ ob, int n)
{
    int i = blockIdx.x*blockDim.x+threadIdx.x;
    if (i < n){ of[i]=a1[i]+a2[i]; ob[i]=b1[i]+b2[i]; }
}

__global__ void zero_f(float* __restrict__ p, int n)
{
    int i = blockIdx.x*blockDim.x+threadIdx.x;
    if (i < n) p[i] = 0.f;
}

// pad Wih (2048 x 557) -> WP (2048 x 560), zero tail
__global__ void pad_w(const float* __restrict__ wf, const float* __restrict__ wb,
                      float* __restrict__ of, float* __restrict__ ob)
{
    int gid = blockIdx.x*blockDim.x + threadIdx.x;
    if (gid >= 2*GW*DDP) return;
    int d = gid / (GW*DDP);
    int r = gid - d*(GW*DDP);
    int j = r / DDP, k = r - j*DDP;
    float v = (k < DD) ? (d ? wb[j*DD+k] : wf[j*DD+k]) : 0.f;
    (d ? ob : of)[r] = v;
}

// ---------------- x assembly: word emb + cap emb + zero pad ---------------------------
__global__ void x_fill(const int* __restrict__ wid, const int* __restrict__ cap,
                       const float* __restrict__ wemb, const float* __restrict__ cemb,
                       float* __restrict__ X)
{
    int gid = blockIdx.x*blockDim.x+threadIdx.x;
    int sb = gid / 304, e = gid - sb*304;
    if (sb >= NSB) return;
    if (e < 300)       X[(size_t)sb*DDP + e]   = wemb[(size_t)wid[sb]*300 + e];
    else if (e == 300) X[(size_t)sb*DDP + 556] = cemb[cap[sb]];
    else               X[(size_t)sb*DDP + 556 + (e-300)] = 0.f;  // cols 557..559
}

// =================== fused char-LSTM step (GEMM + gates), both dirs ====================
__global__ __launch_bounds__(256, 2)
void char_step(const float* __restrict__ WhhF, const float* __restrict__ WhhB,
               const float* __restrict__ PF, const float* __restrict__ PB,
               const int* __restrict__ ci,
               float* __restrict__ CH,   // [dir][h(NSEQ*HC), c(NSEQ*HC)]
               float* __restrict__ X, int kstep)
{
    const int dir = blockIdx.x >> 9;
    const int sbase = (blockIdx.x & 511) * 32;
    const int t = dir ? (WLEN-1-kstep) : kstep;
    const int islast = (kstep == WLEN-1);
    const float* Whh = dir ? WhhB : WhhF;
    const float* P   = dir ? PB : PF;
    float* Hg = CH + (size_t)dir*(2*NSEQ*HC);
    float* Cg = Hg + (size_t)NSEQ*HC;

    __shared__ float As[16][36];
    __shared__ float Bs[16][516];

    const int tid = threadIdx.x;
    const int tr = tid >> 4;   // seq pair 0..15
    const int tc = tid & 15;   // cell group 0..15
    float acc[2][32];
    #pragma unroll
    for (int i=0;i<2;i++)
        #pragma unroll
        for (int j=0;j<32;j++) acc[i][j]=0.f;

    for (int kt=0; kt<HC; kt+=16){
        if (tid < 128){
            int sl = tid >> 2, kq = tid & 3;
            float4 v = *(const float4*)&Hg[(size_t)(sbase+sl)*HC + kt + kq*4];
            As[kq*4+0][sl]=v.x; As[kq*4+1][sl]=v.y; As[kq*4+2][sl]=v.z; As[kq*4+3][sl]=v.w;
        }
        #pragma unroll
        for (int i=0;i<8;i++){
            int e = i*256 + tid;
            int j = e >> 2, kq = e & 3;
            float4 v = *(const float4*)&Whh[(size_t)j*HC + kt + kq*4];
            Bs[kq*4+0][j]=v.x; Bs[kq*4+1][j]=v.y; Bs[kq*4+2][j]=v.z; Bs[kq*4+3][j]=v.w;
        }
        __syncthreads();
        #pragma unroll
        for (int k=0;k<16;k++){
            float a0 = As[k][tr*2], a1 = As[k][tr*2+1];
            #pragma unroll
            for (int T=0;T<4;T++){
                float4 b0 = *(float4*)&Bs[k][T*128 + tc*8];
                float4 b1 = *(float4*)&Bs[k][T*128 + tc*8 + 4];
                float bv[8] = {b0.x,b0.y,b0.z,b0.w,b1.x,b1.y,b1.z,b1.w};
                #pragma unroll
                for (int j=0;j<8;j++){
                    acc[0][T*8+j] += a0*bv[j];
                    acc[1][T*8+j] += a1*bv[j];
                }
            }
        }
        __syncthreads();
    }

    #pragma unroll
    for (int i=0;i<2;i++){
        int seq = sbase + tr*2 + i;
        int cid = ci[seq*WLEN + t];
        const float* Pr = P + (size_t)cid*GC;
        int cell0 = tc*8;
        float4 cold0 = *(float4*)&Cg[(size_t)seq*HC + cell0];
        float4 cold1 = *(float4*)&Cg[(size_t)seq*HC + cell0 + 4];
        float cold[8] = {cold0.x,cold0.y,cold0.z,cold0.w,cold1.x,cold1.y,cold1.z,cold1.w};
        float hv[8], cv[8];
        #pragma unroll
        for (int j=0;j<8;j++){
            int cell = cell0 + j;
            float zi = acc[i][j]     + Pr[cell];
            float zf = acc[i][8+j]   + Pr[128+cell];
            float zg = acc[i][16+j]  + Pr[256+cell];
            float zo = acc[i][24+j]  + Pr[384+cell];
            float cn = sigf(zf)*cold[j] + sigf(zi)*tanhf(zg);
            cv[j] = cn;
            hv[j] = sigf(zo)*tanhf(cn);
        }
        *(float4*)&Cg[(size_t)seq*HC + cell0]     = make_float4(cv[0],cv[1],cv[2],cv[3]);
        *(float4*)&Cg[(size_t)seq*HC + cell0 + 4] = make_float4(cv[4],cv[5],cv[6],cv[7]);
        *(float4*)&Hg[(size_t)seq*HC + cell0]     = make_float4(hv[0],hv[1],hv[2],hv[3]);
        *(float4*)&Hg[(size_t)seq*HC + cell0 + 4] = make_float4(hv[4],hv[5],hv[6],hv[7]);
        if (islast){
            int b = seq >> 8, s = seq & 255;
            size_t xr = (size_t)(s*BATCH + b)*DDP + 300 + dir*HC + cell0;
            *(float4*)&X[xr]     = make_float4(hv[0],hv[1],hv[2],hv[3]);
            *(float4*)&X[xr + 4] = make_float4(hv[4],hv[5],hv[6],hv[7]);
        }
    }
}

// =================== word-LSTM step v3: lane=gate-row, waves=batch ====================
// grid 256 = dir(2) x cellgroup(32, 16 cells) x batchgroup(4, 16 batches).
// lane -> row (g = lane>>4 gate type, c = lane&15 cell); wave w -> 4 batches.
// W slice (64 rows x 512 K) staged in LDS as float4 quads, double-buffered 64-k tiles.
// h read via scalar path (readfirstlane'd batch base -> s_load), Ax added in epilogue.
__global__ __launch_bounds__(256)
void word_step3(const float* __restrict__ AxF, const float* __restrict__ AxB,
                const float* __restrict__ WhhF, const float* __restrict__ WhhB,
                const float* __restrict__ Hprev, float* __restrict__ Hnext,
                float* __restrict__ Cst, float* __restrict__ enc,
                int sstep, int sbaseF, int sbaseB)
{
    const int bx  = blockIdx.x;
    const int dir = bx >> 7;
    const int r7  = bx & 127;
    const int cg  = r7 >> 2;       // 0..31
    const int bg  = r7 & 3;        // 0..3
    const int c0  = cg * 16;
    const int b0  = bg * 16;
    const int s = dir ? (S_LEN-1-sstep) : sstep;
    const int sbase = dir ? sbaseB : sbaseF;
    const float* Ax  = dir ? AxB : AxF;
    const float* Whh = dir ? WhhB : WhhF;
    const float* hp = Hprev + dir*(BATCH*HWID);
    float* hn = Hnext + dir*(BATCH*HWID);
    float* cs = Cst   + dir*(BATCH*HWID);

    __shared__ float4 ws4[2][16][64];   // [buf][kq][row] : 32 KB
    __shared__ float zbuf[16][68];      // [batch-local][row] : 4.25 KB

    const int tid  = threadIdx.x;
    const int lane = tid & 63;
    const int wv   = tid >> 6;          // wave 0..3
    const int g_   = lane >> 4, c_ = lane & 15;
    const size_t wrow = (size_t)(g_*HWID + c0 + c_) * HWID;

    // wave-uniform batch bases (scalar path)
    const float* hb0; const float* hb1; const float* hb2; const float* hb3;
    {
        int bb = b0 + wv*4;
        hb0 = hp + (size_t)__builtin_amdgcn_readfirstlane(bb+0) * HWID;
        hb1 = hp + (size_t)__builtin_amdgcn_readfirstlane(bb+1) * HWID;
        hb2 = hp + (size_t)__builtin_amdgcn_readfirstlane(bb+2) * HWID;
        hb3 = hp + (size_t)__builtin_amdgcn_readfirstlane(bb+3) * HWID;
    }

    float acc0=0.f, acc1=0.f, acc2=0.f, acc3=0.f;

    // prologue: stage tile 0 (k = 0..63)
    #pragma unroll
    for (int i=0;i<4;i++){
        int e = i*256 + tid;           // 0..1023
        int row = e >> 4, kq = e & 15;
        int gg = row >> 4, cc = row & 15;
        ws4[0][kq][row] = *(const float4*)&Whh[(size_t)(gg*HWID + c0 + cc)*HWID + kq*4];
    }
    __syncthreads();

    int buf = 0;
    for (int t=0; t<8; t++){
        float4 pf[4];
        if (t < 7){
            int k0n = (t+1)*64;
            #pragma unroll
            for (int i=0;i<4;i++){
                int e = i*256 + tid;
                int row = e >> 4, kq = e & 15;
                int gg = row >> 4, cc = row & 15;
                pf[i] = *(const float4*)&Whh[(size_t)(gg*HWID + c0 + cc)*HWID + k0n + kq*4];
            }
        }
        const int k0 = t*64;
        #pragma unroll
        for (int kq=0; kq<16; kq++){
            float4 w4 = ws4[buf][kq][lane];
            float4 h0 = *(const float4*)&hb0[k0 + kq*4];
            float4 h1 = *(const float4*)&hb1[k0 + kq*4];
            float4 h2 = *(const float4*)&hb2[k0 + kq*4];
            float4 h3 = *(const float4*)&hb3[k0 + kq*4];
            acc0 += w4.x*h0.x + w4.y*h0.y + w4.z*h0.z + w4.w*h0.w;
            acc1 += w4.x*h1.x + w4.y*h1.y + w4.z*h1.z + w4.w*h1.w;
            acc2 += w4.x*h2.x + w4.y*h2.y + w4.z*h2.z + w4.w*h2.w;
            acc3 += w4.x*h3.x + w4.y*h3.y + w4.z*h3.z + w4.w*h3.w;
        }
        if (t < 7){
            int nb = buf ^ 1;
            #pragma unroll
            for (int i=0;i<4;i++){
                int e = i*256 + tid;
                int row = e >> 4, kq = e & 15;
                ws4[nb][kq][row] = pf[i];
            }
            __syncthreads();
            buf = nb;
        }
    }

    // z partials -> LDS (transposed: [batch-local][row], b32 writes conflict-free)
    zbuf[wv*4+0][lane] = acc0;
    zbuf[wv*4+1][lane] = acc1;
    zbuf[wv*4+2][lane] = acc2;
    zbuf[wv*4+3][lane] = acc3;
    __syncthreads();

    // pointwise: thread -> (bl = tid>>4, c = tid&15)
    {
        int bl = tid >> 4, c = tid & 15;
        int bglob = b0 + bl;
        int cell = c0 + c;
        const float* axr = Ax + ((size_t)((s - sbase)*BATCH + bglob))*GW;
        float zi = zbuf[bl][0*16+c] + axr[0*HWID + cell];
        float zf = zbuf[bl][1*16+c] + axr[1*HWID + cell];
        float zg = zbuf[bl][2*16+c] + axr[2*HWID + cell];
        float zo = zbuf[bl][3*16+c] + axr[3*HWID + cell];
        float cp = cs[bglob*HWID + cell];
        float cn = sigf(zf)*cp + sigf(zi)*tanhf(zg);
        float hv = sigf(zo)*tanhf(cn);
        cs[bglob*HWID + cell] = cn;
        hn[bglob*HWID + cell] = hv;
        enc[((size_t)(s*BATCH+bglob))*(2*HWID) + dir*HWID + cell] = hv;
    }
    (void)wrow;
}

// ---------------- CRF log-likelihood (one wave per batch) ------------------------------
__global__ __launch_bounds__(64)
void crf_loss(const float* __restrict__ logits, const int* __restrict__ tags,
              const float* __restrict__ trans, const float* __restrict__ start,
              const float* __restrict__ endt, float* __restrict__ out)
{
    int b = blockIdx.x, lane = threadIdx.x;
    __shared__ float trs[TT*TT];
    __shared__ float as_[TT];
    __shared__ float red[64];
    for (int i=lane;i<TT*TT;i+=64) trs[i]=trans[i];
    __syncthreads();
    float alpha = (lane<TT) ? (start[lane] + logits[b*TT + lane]) : -1e30f;
    for (int s=1;s<S_LEN;s++){
        if (lane<TT) as_[lane]=alpha;
        __syncthreads();
        if (lane<TT){
            float m = -1e30f;
            for (int f=0;f<TT;f++){ float v=as_[f]+trs[f*TT+lane]; m = fmaxf(m,v); }
            float sm = 0.f;
            for (int f=0;f<TT;f++){ float v=as_[f]+trs[f*TT+lane]; sm += __expf(v-m); }
            alpha = m + __logf(sm) + logits[((size_t)s*BATCH+b)*TT + lane];
        }
        __syncthreads();
    }
    if (lane<TT) red[lane] = alpha + endt[lane];
    __syncthreads();
    float logZ = 0.f;
    if (lane==0){
        float m=-1e30f; for(int i=0;i<TT;i++) m=fmaxf(m,red[i]);
        float sm=0.f;   for(int i=0;i<TT;i++) sm += __expf(red[i]-m);
        logZ = m + __logf(sm);
    }
    __syncthreads();
    float sc = 0.f;
    for (int s=lane;s<S_LEN;s+=64){
        int tg = tags[s*BATCH+b];
        sc += logits[((size_t)s*BATCH+b)*TT + tg];
        if (s+1 < S_LEN){ int t2 = tags[(s+1)*BATCH+b]; sc += trs[tg*TT+t2]; }
    }
    red[lane]=sc; __syncthreads();
    if (lane==0){
        float tot = 0.f; for (int i=0;i<64;i++) tot += red[i];
        tot += start[tags[b]] + endt[tags[(S_LEN-1)*BATCH + b]];
        atomicAdd(out, -(tot - logZ));
    }
}

// ---------------- Viterbi (one wave per batch) -----------------------------------------
__global__ __launch_bounds__(64)
void viterbi_k(const float* __restrict__ logits, const float* __restrict__ trans,
               const float* __restrict__ start, const float* __restrict__ endt,
               int* __restrict__ bp, float* __restrict__ outTags)
{
    int b = blockIdx.x, lane = threadIdx.x;
    __shared__ float trs[TT*TT];
    __shared__ float vs_[TT];
    for (int i=lane;i<TT*TT;i+=64) trs[i]=trans[i];
    __syncthreads();
    float v = (lane<TT) ? (start[lane] + logits[b*TT+lane]) : -1e30f;
    for (int s=1;s<S_LEN;s++){
        if (lane<TT) vs_[lane]=v;
        __syncthreads();
        if (lane<TT){
            float best=-1e30f; int bj=0;
            for (int f=0;f<TT;f++){
                float val = vs_[f]+trs[f*TT+lane];
                if (val > best){ best=val; bj=f; }   // strict >: first max (jnp.argmax)
            }
            v = best + logits[((size_t)s*BATCH+b)*TT+lane];
            bp[((size_t)(s-1)*BATCH+b)*TT + lane] = bj;
        }
        __syncthreads();
    }
    if (lane<TT) vs_[lane] = v + endt[lane];
    __syncthreads();
    if (lane==0){
        float best=-1e30f; int last=0;
        for (int i=0;i<TT;i++){ if (vs_[i] > best){best=vs_[i]; last=i;} }
        int tag=last;
        outTags[b*S_LEN + (S_LEN-1)] = (float)tag;
        for (int s=S_LEN-2;s>=0;s--){
            tag = bp[((size_t)s*BATCH+b)*TT + tag];
            outTags[b*S_LEN + s] = (float)tag;
        }
    }
}

// ======================================================================================
extern "C" void kernel_launch(void* const* d_in, const int* in_sizes, int n_in,
                              void* d_out, int out_size, void* d_ws, size_t ws_size,
                              hipStream_t stream)
{
    const int* word_in = (const int*)d_in[0];
    const int* char_in = (const int*)d_in[1];
    const int* cap_in  = (const int*)d_in[2];
    const int* tag_in  = (const int*)d_in[3];
    const float* wemb  = (const float*)d_in[4];
    const float* cemb  = (const float*)d_in[5];
    const float* chemb = (const float*)d_in[6];
    const float* cWihF=(const float*)d_in[7],  *cWhhF=(const float*)d_in[8];
    const float* cBihF=(const float*)d_in[9],  *cBhhF=(const float*)d_in[10];
    const float* cWihB=(const float*)d_in[11], *cWhhB=(const float*)d_in[12];
    const float* cBihB=(const float*)d_in[13], *cBhhB=(const float*)d_in[14];
    const float* wWihF=(const float*)d_in[15], *wWhhF=(const float*)d_in[16];
    const float* wBihF=(const float*)d_in[17], *wBhhF=(const float*)d_in[18];
    const float* wWihB=(const float*)d_in[19], *wWhhB=(const float*)d_in[20];
    const float* wBihB=(const float*)d_in[21], *wBhhB=(const float*)d_in[22];
    const float* ff1W=(const float*)d_in[23],  *ff1b=(const float*)d_in[24];
    const float* ff2W=(const float*)d_in[25],  *ff2b=(const float*)d_in[26];
    const float* trans=(const float*)d_in[27];
    const float* startT=(const float*)d_in[28], *endT=(const float*)d_in[29];
    float* out = (float*)d_out;

    // ---- workspace layout (floats) -----------------------------------------
    float* W = (float*)d_ws;
    size_t o = 0;
    float* X    = W + o; o += (size_t)NSB*DDP;          //  9.18M
    float* AXCF = W + o; o += (size_t)CROWS*GW;         //  4.19M
    float* AXCB = W + o; o += (size_t)CROWS*GW;         //  4.19M
    float* ENC  = W + o; o += (size_t)NSB*2*HWID;       // 16.78M
    float* PF   = W + o; o += 128*GC;
    float* PB   = W + o; o += 128*GC;
    float* BSF  = W + o; o += GW;
    float* BSB  = W + o; o += GW;
    float* HWb  = W + o; o += (size_t)2*2*BATCH*HWID;
    float* CW   = W + o; o += (size_t)2*BATCH*HWID;
    float* WPF  = W + o; o += (size_t)GW*DDP;
    float* WPB  = W + o; o += (size_t)GW*DDP;
    // aliases (disjoint in time)
    float* CH  = ENC;            // char h/c: 4*NSEQ*HC = 8.39M <= ENC
    float* HFF = AXCF;           // ff1 hidden 16384x512 (AXCF+AXCB span)
    float* LOG = X;              // logits 16384x32 (X dead after word phase)
    int*   BP  = (int*)(X + (size_t)1024*1024);

    dim3 blk(256);

    // ---- precomputes -------------------------------------------------------
    char_pmat<<<(2*128*GC+255)/256, blk, 0, stream>>>(chemb, cWihF, cWihB,
                                                      cBihF, cBhhF, cBihB, cBhhB, PF, PB);
    x_fill<<<((NSB*304)+255)/256, blk, 0, stream>>>(word_in, cap_in, wemb, cemb, X);
    bias_sum<<<(GW+255)/256, blk, 0, stream>>>(wBihF, wBhhF, wBihB, wBhhB, BSF, BSB, GW);
    pad_w<<<(2*GW*DDP+255)/256, blk, 0, stream>>>(wWihF, wWihB, WPF, WPB);

    // ---- char BiLSTM (fused, both dirs per launch) -------------------------
    zero_f<<<(4*NSEQ*HC+255)/256, blk, 0, stream>>>(CH, 4*NSEQ*HC);
    for (int k=0;k<WLEN;k++){
        char_step<<<1024, blk, 0, stream>>>(cWhhF, cWhhB, PF, PB, char_in, CH, X, k);
    }

    // ---- word BiLSTM, chunked input projection -----------------------------
    zero_f<<<(2*BATCH*HWID+255)/256, blk, 0, stream>>>(HWb, 2*BATCH*HWID);
    zero_f<<<(2*BATCH*HWID+255)/256, blk, 0, stream>>>(CW,  2*BATCH*HWID);
    dim3 gax(CROWS/BM, GW/BN);   // (16, 16)
    for (int j=0;j<S_LEN/CHUNK;j++){
        int sbf = j*CHUNK;
        int sbb = (S_LEN-CHUNK) - j*CHUNK;
        gemm128<<<gax, blk, 0, stream>>>(X + (size_t)sbf*BATCH*DDP, DDP, WPF, DDP,
                                         AXCF, GW, CROWS, GW, DDP, BSF, 0);
        gemm128<<<gax, blk, 0, stream>>>(X + (size_t)sbb*BATCH*DDP, DDP, WPB, DDP,
                                         AXCB, GW, CROWS, GW, DDP, BSB, 0);
        for (int t=0;t<CHUNK;t++){
            int ss = j*CHUNK + t;
            int par = ss & 1;
            word_step3<<<256, blk, 0, stream>>>(AXCF, AXCB, wWhhF, wWhhB,
                HWb + (size_t)par*2*BATCH*HWID,
                HWb + (size_t)(1-par)*2*BATCH*HWID,
                CW, ENC, ss, sbf, sbb);
        }
    }

    // ---- feed-forward head -------------------------------------------------
    dim3 g1(NSB/BM, HWID/BN);    // (128, 4)
    gemm128<<<g1, blk, 0, stream>>>(ENC, 2*HWID, ff1W, 2*HWID, HFF, HWID,
                                    NSB, HWID, 2*HWID, ff1b, 1);
    dim3 g2(NSB/BM, 1);
    gemm128<<<g2, blk, 0, stream>>>(HFF, HWID, ff2W, HWID, LOG, TT,
                                    NSB, TT, HWID, ff2b, 0);

    // ---- CRF loss + Viterbi ------------------------------------------------
    zero_f<<<1, dim3(64), 0, stream>>>(out, 1);
    crf_loss<<<BATCH, dim3(64), 0, stream>>>(LOG, tag_in, trans, startT, endT, out);
    viterbi_k<<<BATCH, dim3(64), 0, stream>>>(LOG, trans, startT, endT, BP, out+1);
}

// Round 6
// 8398.574 us; speedup vs baseline: 1.4390x; 1.4390x over previous
//
#include <hip/hip_runtime.h>
#include <math.h>

// Problem constants
#define S_LEN 256
#define BATCH 64
#define WLEN  16
#define EC    64
#define HC    128
#define HWID  512
#define TT    32
#define DD    557
#define DDP   576    // padded K for MFMA (mult of 32)
#define NSEQ  16384
#define NSB   16384
#define GC    512    // 4*HC
#define GW    2048   // 4*HWID
#define CHUNK 32
#define CROWS (CHUNK*BATCH)   // 2048

typedef unsigned short u16;
typedef __attribute__((ext_vector_type(8))) short bf16x8;
typedef __attribute__((ext_vector_type(4))) float f32x4;

__device__ __forceinline__ float sigf(float x){ return 1.f/(1.f+__expf(-x)); }

// split fp32 -> (hi, lo) bf16 by bit truncation; v ~= hi + lo with ~16 mantissa bits
__device__ __forceinline__ void split2(float v, u16& h, u16& l){
    unsigned int u = __float_as_uint(v);
    h = (u16)(u >> 16);
    float r = v - __uint_as_float(u & 0xffff0000u);
    l = (u16)(__float_as_uint(r) >> 16);
}

// =================== fp32 GEMM (kept for ff2, small N) ================================
#define BM 128
#define BN 128
#define BK 16
__global__ __launch_bounds__(256, 2)
void gemm128(const float* __restrict__ A, int lda,
             const float* __restrict__ Bm, int ldb,
             float* __restrict__ C, int ldc,
             int M, int N, int K,
             const float* __restrict__ bias, int act)
{
    __shared__ float As[BK][BM+4];
    __shared__ float Bs[BK][BN+4];
    const int tid = threadIdx.x;
    const int m0 = blockIdx.x * BM;
    const int n0 = blockIdx.y * BN;
    const int tr = tid >> 4;
    const int tc = tid & 15;
    float acc[8][8];
    #pragma unroll
    for (int i=0;i<8;i++)
        #pragma unroll
        for(int j=0;j<8;j++) acc[i][j]=0.f;

    for (int k0 = 0; k0 < K; k0 += BK) {
        #pragma unroll
        for (int i=0;i<2;i++){
            int e = i*256 + tid;
            int m = e >> 2, kq = e & 3;
            int gm = m0 + m;
            float4 v = make_float4(0.f,0.f,0.f,0.f);
            if (gm < M) v = *(const float4*)&A[(size_t)gm*lda + k0 + kq*4];
            As[kq*4+0][m]=v.x; As[kq*4+1][m]=v.y; As[kq*4+2][m]=v.z; As[kq*4+3][m]=v.w;
        }
        #pragma unroll
        for (int i=0;i<2;i++){
            int e = i*256 + tid;
            int n = e >> 2, kq = e & 3;
            int gn = n0 + n;
            float4 v = make_float4(0.f,0.f,0.f,0.f);
            if (gn < N) v = *(const float4*)&Bm[(size_t)gn*ldb + k0 + kq*4];
            Bs[kq*4+0][n]=v.x; Bs[kq*4+1][n]=v.y; Bs[kq*4+2][n]=v.z; Bs[kq*4+3][n]=v.w;
        }
        __syncthreads();
        #pragma unroll
        for (int k = 0; k < BK; k++) {
            float4 a0 = *(float4*)&As[k][tr*8];
            float4 a1 = *(float4*)&As[k][tr*8+4];
            float4 b0 = *(float4*)&Bs[k][tc*8];
            float4 b1 = *(float4*)&Bs[k][tc*8+4];
            float av[8] = {a0.x,a0.y,a0.z,a0.w,a1.x,a1.y,a1.z,a1.w};
            float bv[8] = {b0.x,b0.y,b0.z,b0.w,b1.x,b1.y,b1.z,b1.w};
            #pragma unroll
            for (int i=0;i<8;i++)
                #pragma unroll
                for (int j=0;j<8;j++)
                    acc[i][j] += av[i]*bv[j];
        }
        __syncthreads();
    }
    #pragma unroll
    for (int i=0;i<8;i++){
        int m = m0 + tr*8 + i;
        if (m >= M) continue;
        #pragma unroll
        for (int j=0;j<8;j++){
            int n = n0 + tc*8 + j;
            if (n >= N) continue;
            float v = acc[i][j];
            if (bias) v += bias[n];
            if (act==1) v = tanhf(v);
            C[(size_t)m*ldc + n] = v;
        }
    }
}

// ============ MFMA split-bf16 GEMM: C = act(A(MxK)*B(NxK)^T + bias) ===================
// A,B pre-split into hi/lo bf16 ushort arrays (K-contiguous). M,N % 128 == 0, K % 32 == 0.
// Block 256 thr = 4 waves; wave tile 64x64 (4x4 of 16x16x32 MFMA).
// NOTE: staging moves 32 ushorts/row = 2 x uint4 per thread per array (uint4 = 8 u16!).
__global__ __launch_bounds__(256, 2)
void gemm_mfma(const u16* __restrict__ Ah, const u16* __restrict__ Al, int lda,
               const u16* __restrict__ Bh, const u16* __restrict__ Bl, int ldb,
               float* __restrict__ C, int ldc, int K,
               const float* __restrict__ bias, int act)
{
    __shared__ u16 AsH[128*40], AsL[128*40], BsH[128*40], BsL[128*40];
    const int tid  = threadIdx.x;
    const int lane = tid & 63, wv = tid >> 6;
    const int m0 = blockIdx.x * 128, n0 = blockIdx.y * 128;
    const int wm = (wv >> 1) * 64, wn = (wv & 1) * 64;
    const int quad = lane >> 4, l15 = lane & 15;
    const int sr = tid >> 1;            // staging row 0..127
    const int sh = (tid & 1) * 16;      // staging k-half: u16 offset 0 or 16

    f32x4 acc[4][4];
    #pragma unroll
    for (int i=0;i<4;i++)
        #pragma unroll
        for (int j=0;j<4;j++){ f32x4 z = {0.f,0.f,0.f,0.f}; acc[i][j] = z; }

    for (int kc = 0; kc < K; kc += 32){
        const size_t ra = (size_t)(m0+sr)*lda + kc + sh;
        const size_t rb = (size_t)(n0+sr)*ldb + kc + sh;
        uint4 a0 = *(const uint4*)&Ah[ra];
        uint4 a1 = *(const uint4*)&Ah[ra + 8];
        uint4 l0 = *(const uint4*)&Al[ra];
        uint4 l1 = *(const uint4*)&Al[ra + 8];
        uint4 b0 = *(const uint4*)&Bh[rb];
        uint4 b1 = *(const uint4*)&Bh[rb + 8];
        uint4 c0 = *(const uint4*)&Bl[rb];
        uint4 c1 = *(const uint4*)&Bl[rb + 8];
        *(uint4*)&AsH[sr*40 + sh]     = a0;
        *(uint4*)&AsH[sr*40 + sh + 8] = a1;
        *(uint4*)&AsL[sr*40 + sh]     = l0;
        *(uint4*)&AsL[sr*40 + sh + 8] = l1;
        *(uint4*)&BsH[sr*40 + sh]     = b0;
        *(uint4*)&BsH[sr*40 + sh + 8] = b1;
        *(uint4*)&BsL[sr*40 + sh]     = c0;
        *(uint4*)&BsL[sr*40 + sh + 8] = c1;
        __syncthreads();

        bf16x8 afh[4], afl[4], bfh[4], bfl[4];
        #pragma unroll
        for (int mt=0; mt<4; mt++){
            int r = wm + mt*16 + l15;
            afh[mt] = *(const bf16x8*)&AsH[r*40 + quad*8];
            afl[mt] = *(const bf16x8*)&AsL[r*40 + quad*8];
        }
        #pragma unroll
        for (int nt=0; nt<4; nt++){
            int r = wn + nt*16 + l15;
            bfh[nt] = *(const bf16x8*)&BsH[r*40 + quad*8];
            bfl[nt] = *(const bf16x8*)&BsL[r*40 + quad*8];
        }
        #pragma unroll
        for (int mt=0; mt<4; mt++)
            #pragma unroll
            for (int nt=0; nt<4; nt++){
                acc[mt][nt] = __builtin_amdgcn_mfma_f32_16x16x32_bf16(afh[mt], bfh[nt], acc[mt][nt], 0,0,0);
                acc[mt][nt] = __builtin_amdgcn_mfma_f32_16x16x32_bf16(afh[mt], bfl[nt], acc[mt][nt], 0,0,0);
                acc[mt][nt] = __builtin_amdgcn_mfma_f32_16x16x32_bf16(afl[mt], bfh[nt], acc[mt][nt], 0,0,0);
            }
        __syncthreads();
    }

    // epilogue: D[row=quad*4+r][col=l15]
    #pragma unroll
    for (int mt=0; mt<4; mt++)
        #pragma unroll
        for (int nt=0; nt<4; nt++){
            int n = n0 + wn + nt*16 + l15;
            float bv = bias ? bias[n] : 0.f;
            #pragma unroll
            for (int r=0;r<4;r++){
                int m = m0 + wm + mt*16 + quad*4 + r;
                float v = acc[mt][nt][r] + bv;
                if (act==1) v = tanhf(v);
                C[(size_t)m*ldc + n] = v;
            }
        }
}

// ============ P[v][j] = char_emb(v,:) . Wih(j,:) + bih[j] + bhh[j], per dir ===========
__global__ void char_pmat(const float* __restrict__ ce,
                          const float* __restrict__ wf, const float* __restrict__ wb,
                          const float* __restrict__ bihF, const float* __restrict__ bhhF,
                          const float* __restrict__ bihB, const float* __restrict__ bhhB,
                          float* __restrict__ Pf, float* __restrict__ Pb)
{
    int gid = blockIdx.x*blockDim.x + threadIdx.x;
    if (gid >= 2*128*GC) return;
    int d = gid >> 16;
    int r = gid & 65535;
    int v = r >> 9, j = r & 511;
    const float* wW = d ? wb : wf;
    float s = 0.f;
    for (int e=0;e<EC;e++) s += ce[v*EC+e]*wW[j*EC+e];
    s += (d ? bihB[j]+bhhB[j] : bihF[j]+bhhF[j]);
    (d ? Pb : Pf)[r] = s;
}

__global__ void bias_sum(const float* __restrict__ a1, const float* __restrict__ a2,
                         const float* __restrict__ b1, const float* __restrict__ b2,
                         float* __restrict__ of, float* __restrict__ ob, int n)
{
    int i = blockIdx.x*blockDim.x+threadIdx.x;
    if (i < n){ of[i]=a1[i]+a2[i]; ob[i]=b1[i]+b2[i]; }
}

__global__ void zero_f(float* __restrict__ p, int n)
{
    int i = blockIdx.x*blockDim.x+threadIdx.x;
    if (i < n) p[i] = 0.f;
}

__global__ void split_pair(const float* __restrict__ src, u16* __restrict__ hi,
                           u16* __restrict__ lo, int n)
{
    int i = blockIdx.x*blockDim.x+threadIdx.x;
    if (i < n){ u16 h,l; split2(src[i],h,l); hi[i]=h; lo[i]=l; }
}

// pad word Wih (2048 x 557) -> hi/lo pairs (2048 x 576), zero tail
__global__ void pad_w_split(const float* __restrict__ wf, const float* __restrict__ wb,
                            u16* __restrict__ ofh, u16* __restrict__ ofl,
                            u16* __restrict__ obh, u16* __restrict__ obl)
{
    int gid = blockIdx.x*blockDim.x + threadIdx.x;
    if (gid >= 2*GW*DDP) return;
    int d = gid / (GW*DDP);
    int r = gid - d*(GW*DDP);
    int j = r / DDP, k = r - j*DDP;
    float v = (k < DD) ? (d ? wb[(size_t)j*DD+k] : wf[(size_t)j*DD+k]) : 0.f;
    u16 h,l; split2(v,h,l);
    if (d){ obh[r]=h; obl[r]=l; } else { ofh[r]=h; ofl[r]=l; }
}

// x assembly directly into bf16 pairs: word emb + cap + zero pad
__global__ void x_fill_pair(const int* __restrict__ wid, const int* __restrict__ cap,
                            const float* __restrict__ wemb, const float* __restrict__ cemb,
                            u16* __restrict__ Xh, u16* __restrict__ Xl)
{
    int gid = blockIdx.x*blockDim.x+threadIdx.x;
    int sb = gid / 320, e = gid - sb*320;
    if (sb >= NSB) return;
    float v; int col;
    if (e < 300){ v = wemb[(size_t)wid[sb]*300 + e]; col = e; }
    else if (e == 300){ v = cemb[cap[sb]]; col = 556; }
    else { v = 0.f; col = 556 + (e-300); }   // cols 557..575
    u16 h,l; split2(v,h,l);
    size_t idx = (size_t)sb*DDP + col;
    Xh[idx]=h; Xl[idx]=l;
}

// =================== char-LSTM step via MFMA (both dirs) ==============================
// grid 1024 = dir(2) x seqblock(512 of 32 seqs). Block: 32 seqs x 512 gates, K=128.
// A = h pairs (seq-major), B = cWhh pairs (gate-major); direct global fragment loads
// (bf16x8 = 8 u16 = 16 B, correctly sized).
__global__ __launch_bounds__(256, 2)
void char_step_mfma(const u16* __restrict__ cWFh, const u16* __restrict__ cWFl,
                    const u16* __restrict__ cWBh, const u16* __restrict__ cWBl,
                    const float* __restrict__ PF, const float* __restrict__ PB,
                    const int* __restrict__ ci,
                    u16* __restrict__ Hh, u16* __restrict__ Hl, float* __restrict__ Cc,
                    u16* __restrict__ Xh, u16* __restrict__ Xl, int kstep)
{
    const int dir = blockIdx.x >> 9;
    const int s0  = (blockIdx.x & 511) * 32;
    const int t = dir ? (WLEN-1-kstep) : kstep;
    const int islast = (kstep == WLEN-1);
    const u16* Wh = dir ? cWBh : cWFh;
    const u16* Wl = dir ? cWBl : cWFl;
    const float* P = dir ? PB : PF;
    u16* hh = Hh + (size_t)dir*NSEQ*HC;
    u16* hl = Hl + (size_t)dir*NSEQ*HC;
    float* cc = Cc + (size_t)dir*NSEQ*HC;

    __shared__ float zs[32*512];   // swizzled: idx = m*512 + ((col + 2m) & 511)

    const int tid = threadIdx.x;
    const int lane = tid & 63, wv = tid >> 6;
    const int quad = lane >> 4, l15 = lane & 15;
    const int n0w = wv * 128;

    f32x4 acc[2][8];
    #pragma unroll
    for (int i=0;i<2;i++)
        #pragma unroll
        for (int j=0;j<8;j++){ f32x4 z = {0.f,0.f,0.f,0.f}; acc[i][j] = z; }

    #pragma unroll
    for (int kc=0; kc<HC; kc+=32){
        bf16x8 ah[2], al[2];
        #pragma unroll
        for (int mt=0; mt<2; mt++){
            size_t p = (size_t)(s0 + mt*16 + l15)*HC + kc + quad*8;
            ah[mt] = *(const bf16x8*)&hh[p];
            al[mt] = *(const bf16x8*)&hl[p];
        }
        #pragma unroll
        for (int nt=0; nt<8; nt++){
            size_t p = (size_t)(n0w + nt*16 + l15)*HC + kc + quad*8;
            bf16x8 bh = *(const bf16x8*)&Wh[p];
            bf16x8 bl = *(const bf16x8*)&Wl[p];
            #pragma unroll
            for (int mt=0; mt<2; mt++){
                acc[mt][nt] = __builtin_amdgcn_mfma_f32_16x16x32_bf16(ah[mt], bh, acc[mt][nt], 0,0,0);
                acc[mt][nt] = __builtin_amdgcn_mfma_f32_16x16x32_bf16(ah[mt], bl, acc[mt][nt], 0,0,0);
                acc[mt][nt] = __builtin_amdgcn_mfma_f32_16x16x32_bf16(al[mt], bh, acc[mt][nt], 0,0,0);
            }
        }
    }

    // z -> LDS (swizzled)
    #pragma unroll
    for (int mt=0; mt<2; mt++)
        #pragma unroll
        for (int nt=0; nt<8; nt++){
            int col = n0w + nt*16 + l15;
            #pragma unroll
            for (int r=0;r<4;r++){
                int m = mt*16 + quad*4 + r;
                zs[m*512 + ((col + 2*m) & 511)] = acc[mt][nt][r];
            }
        }
    __syncthreads();

    // pointwise: thread -> seq-local sl = tid>>3 (0..31), cellgroup cg = tid&7 (16 cells)
    {
        int sl = tid >> 3, cg = tid & 7;
        int seq = s0 + sl;
        int cid = ci[seq*WLEN + t];
        const float* Pr = P + (size_t)cid*GC;
        int b = seq >> 8, s = seq & 255;
        size_t xbase = (size_t)(s*BATCH + b)*DDP + 300 + dir*HC;
        #pragma unroll
        for (int j=0;j<16;j++){
            int cell = cg*16 + j;
            float zi = zs[sl*512 + ((cell       + 2*sl) & 511)] + Pr[cell];
            float zf = zs[sl*512 + ((cell + 128 + 2*sl) & 511)] + Pr[128+cell];
            float zg = zs[sl*512 + ((cell + 256 + 2*sl) & 511)] + Pr[256+cell];
            float zo = zs[sl*512 + ((cell + 384 + 2*sl) & 511)] + Pr[384+cell];
            size_t ix = (size_t)seq*HC + cell;
            float cp = cc[ix];
            float cn = sigf(zf)*cp + sigf(zi)*tanhf(zg);
            float hv = sigf(zo)*tanhf(cn);
            cc[ix] = cn;
            u16 h_,l_; split2(hv,h_,l_);
            hh[ix]=h_; hl[ix]=l_;
            if (islast){ Xh[xbase+cell]=h_; Xl[xbase+cell]=l_; }
        }
    }
}

// =================== word-LSTM step v2 (proven) =======================================
// grid 256: dir = blk>>7, slice = blk&127 -> 4 cells (16 gate rows) x 64 batch.
__global__ __launch_bounds__(256)
void word_step(const float* __restrict__ AxF, const float* __restrict__ AxB,
               const float* __restrict__ WhhF, const float* __restrict__ WhhB,
               const float* __restrict__ Hprev, float* __restrict__ Hnext,
               float* __restrict__ Cst,
               u16* __restrict__ Eh, u16* __restrict__ El,
               int sstep, int sbaseF, int sbaseB)
{
    const int dir = blockIdx.x >> 7;
    const int slice = blockIdx.x & 127;
    const int c0 = slice * 4;
    const int s = dir ? (S_LEN-1-sstep) : sstep;
    const int sbase = dir ? sbaseB : sbaseF;
    const float* Ax  = dir ? AxB : AxF;
    const float* Whh = dir ? WhhB : WhhF;
    const float* hp = Hprev + dir*(BATCH*HWID);
    float* hn = Hnext + dir*(BATCH*HWID);
    float* cs = Cst   + dir*(BATCH*HWID);

    __shared__ float hs_[32][65];
    __shared__ float ws_[32][20];
    __shared__ float zbuf[BATCH][20];

    const int tid = threadIdx.x;
    const int bi = tid & 63;
    const int rg = tid >> 6;
    float acc[4];
    #pragma unroll
    for (int i=0;i<4;i++) acc[i]=0.f;

    for (int k0=0;k0<HWID;k0+=32){
        #pragma unroll
        for (int i=0;i<2;i++){
            int e = i*256+tid; int b = e>>3, kq = e&7;
            float4 v = *(const float4*)&hp[b*HWID + k0 + kq*4];
            hs_[kq*4+0][b]=v.x; hs_[kq*4+1][b]=v.y; hs_[kq*4+2][b]=v.z; hs_[kq*4+3][b]=v.w;
        }
        if (tid < 128){
            int r = tid>>3, kq = tid&7;
            int j = (r>>2)*HWID + c0 + (r&3);
            float4 v = *(const float4*)&Whh[(size_t)j*HWID + k0 + kq*4];
            ws_[kq*4+0][r]=v.x; ws_[kq*4+1][r]=v.y; ws_[kq*4+2][r]=v.z; ws_[kq*4+3][r]=v.w;
        }
        __syncthreads();
        #pragma unroll
        for (int k=0;k<32;k++){
            float hv = hs_[k][bi];
            float4 w = *(float4*)&ws_[k][rg*4];
            acc[0] += hv*w.x; acc[1] += hv*w.y; acc[2] += hv*w.z; acc[3] += hv*w.w;
        }
        __syncthreads();
    }
    {
        const float* axr = Ax + ((size_t)((s - sbase)*BATCH + bi))*GW + rg*HWID + c0;
        float4 ax = *(const float4*)axr;
        *(float4*)&zbuf[bi][rg*4] = make_float4(acc[0]+ax.x, acc[1]+ax.y, acc[2]+ax.z, acc[3]+ax.w);
    }
    __syncthreads();
    {
        int b = tid >> 2, ci2 = tid & 3;
        float zi = zbuf[b][ci2], zf = zbuf[b][4+ci2];
        float zg = zbuf[b][8+ci2], zo = zbuf[b][12+ci2];
        int cell = c0 + ci2;
        float cp = cs[b*HWID+cell];
        float cn = sigf(zf)*cp + sigf(zi)*tanhf(zg);
        float hv = sigf(zo)*tanhf(cn);
        cs[b*HWID+cell]=cn;
        hn[b*HWID+cell]=hv;
        u16 h_,l_; split2(hv,h_,l_);
        size_t ei = ((size_t)(s*BATCH+b))*(2*HWID) + dir*HWID + cell;
        Eh[ei]=h_; El[ei]=l_;
    }
}

// ---------------- CRF log-likelihood (one wave per batch) ------------------------------
__global__ __launch_bounds__(64)
void crf_loss(const float* __restrict__ logits, const int* __restrict__ tags,
              const float* __restrict__ trans, const float* __restrict__ start,
              const float* __restrict__ endt, float* __restrict__ out)
{
    int b = blockIdx.x, lane = threadIdx.x;
    __shared__ float trs[TT*TT];
    __shared__ float as_[TT];
    __shared__ float red[64];
    for (int i=lane;i<TT*TT;i+=64) trs[i]=trans[i];
    __syncthreads();
    float alpha = (lane<TT) ? (start[lane] + logits[b*TT + lane]) : -1e30f;
    for (int s=1;s<S_LEN;s++){
        if (lane<TT) as_[lane]=alpha;
        __syncthreads();
        if (lane<TT){
            float m = -1e30f;
            for (int f=0;f<TT;f++){ float v=as_[f]+trs[f*TT+lane]; m = fmaxf(m,v); }
            float sm = 0.f;
            for (int f=0;f<TT;f++){ float v=as_[f]+trs[f*TT+lane]; sm += __expf(v-m); }
            alpha = m + __logf(sm) + logits[((size_t)s*BATCH+b)*TT + lane];
        }
        __syncthreads();
    }
    if (lane<TT) red[lane] = alpha + endt[lane];
    __syncthreads();
    float logZ = 0.f;
    if (lane==0){
        float m=-1e30f; for(int i=0;i<TT;i++) m=fmaxf(m,red[i]);
        float sm=0.f;   for(int i=0;i<TT;i++) sm += __expf(red[i]-m);
        logZ = m + __logf(sm);
    }
    __syncthreads();
    float sc = 0.f;
    for (int s=lane;s<S_LEN;s+=64){
        int tg = tags[s*BATCH+b];
        sc += logits[((size_t)s*BATCH+b)*TT + tg];
        if (s+1 < S_LEN){ int t2 = tags[(s+1)*BATCH+b]; sc += trs[tg*TT+t2]; }
    }
    red[lane]=sc; __syncthreads();
    if (lane==0){
        float tot = 0.f; for (int i=0;i<64;i++) tot += red[i];
        tot += start[tags[b]] + endt[tags[(S_LEN-1)*BATCH + b]];
        atomicAdd(out, -(tot - logZ));
    }
}

// ---------------- Viterbi (one wave per batch) -----------------------------------------
__global__ __launch_bounds__(64)
void viterbi_k(const float* __restrict__ logits, const float* __restrict__ trans,
               const float* __restrict__ start, const float* __restrict__ endt,
               int* __restrict__ bp, float* __restrict__ outTags)
{
    int b = blockIdx.x, lane = threadIdx.x;
    __shared__ float trs[TT*TT];
    __shared__ float vs_[TT];
    for (int i=lane;i<TT*TT;i+=64) trs[i]=trans[i];
    __syncthreads();
    float v = (lane<TT) ? (start[lane] + logits[b*TT+lane]) : -1e30f;
    for (int s=1;s<S_LEN;s++){
        if (lane<TT) vs_[lane]=v;
        __syncthreads();
        if (lane<TT){
            float best=-1e30f; int bj=0;
            for (int f=0;f<TT;f++){
                float val = vs_[f]+trs[f*TT+lane];
                if (val > best){ best=val; bj=f; }
            }
            v = best + logits[((size_t)s*BATCH+b)*TT+lane];
            bp[((size_t)(s-1)*BATCH+b)*TT + lane] = bj;
        }
        __syncthreads();
    }
    if (lane<TT) vs_[lane] = v + endt[lane];
    __syncthreads();
    if (lane==0){
        float best=-1e30f; int last=0;
        for (int i=0;i<TT;i++){ if (vs_[i] > best){best=vs_[i]; last=i;} }
        int tag=last;
        outTags[b*S_LEN + (S_LEN-1)] = (float)tag;
        for (int s=S_LEN-2;s>=0;s--){
            tag = bp[((size_t)s*BATCH+b)*TT + tag];
            outTags[b*S_LEN + s] = (float)tag;
        }
    }
}

// ======================================================================================
extern "C" void kernel_launch(void* const* d_in, const int* in_sizes, int n_in,
                              void* d_out, int out_size, void* d_ws, size_t ws_size,
                              hipStream_t stream)
{
    const int* word_in = (const int*)d_in[0];
    const int* char_in = (const int*)d_in[1];
    const int* cap_in  = (const int*)d_in[2];
    const int* tag_in  = (const int*)d_in[3];
    const float* wemb  = (const float*)d_in[4];
    const float* cemb  = (const float*)d_in[5];
    const float* chemb = (const float*)d_in[6];
    const float* cWihF=(const float*)d_in[7],  *cWhhF=(const float*)d_in[8];
    const float* cBihF=(const float*)d_in[9],  *cBhhF=(const float*)d_in[10];
    const float* cWihB=(const float*)d_in[11], *cWhhB=(const float*)d_in[12];
    const float* cBihB=(const float*)d_in[13], *cBhhB=(const float*)d_in[14];
    const float* wWihF=(const float*)d_in[15], *wWhhF=(const float*)d_in[16];
    const float* wBihF=(const float*)d_in[17], *wBhhF=(const float*)d_in[18];
    const float* wWihB=(const float*)d_in[19], *wWhhB=(const float*)d_in[20];
    const float* wBihB=(const float*)d_in[21], *wBhhB=(const float*)d_in[22];
    const float* ff1W=(const float*)d_in[23],  *ff1b=(const float*)d_in[24];
    const float* ff2W=(const float*)d_in[25],  *ff2b=(const float*)d_in[26];
    const float* trans=(const float*)d_in[27];
    const float* startT=(const float*)d_in[28], *endT=(const float*)d_in[29];
    float* out = (float*)d_out;

    // ---- workspace layout (fl units), ~152 MB ------------------------------
    float* W = (float*)d_ws;
    size_t o = 0;
    float* XhF  = W + o; o += (size_t)NSB*DDP/2;      // X hi pairs (ushort)
    float* XlF  = W + o; o += (size_t)NSB*DDP/2;
    float* AXCF = W + o; o += (size_t)CROWS*GW;
    float* AXCB = W + o; o += (size_t)CROWS*GW;
    float* EhF  = W + o; o += (size_t)NSB*1024/2;     // ENC hi pairs
    float* ElF  = W + o; o += (size_t)NSB*1024/2;
    float* PF   = W + o; o += 128*GC;
    float* PB   = W + o; o += 128*GC;
    float* BSF  = W + o; o += GW;
    float* BSB  = W + o; o += GW;
    float* HWb  = W + o; o += (size_t)2*2*BATCH*HWID;
    float* CW   = W + o; o += (size_t)2*BATCH*HWID;
    float* WFh  = W + o; o += (size_t)GW*DDP/2;       // word Wih pairs
    float* WFl  = W + o; o += (size_t)GW*DDP/2;
    float* WBh  = W + o; o += (size_t)GW*DDP/2;
    float* WBl  = W + o; o += (size_t)GW*DDP/2;
    float* cFh  = W + o; o += (size_t)GC*HC/2;        // char Whh pairs
    float* cFl  = W + o; o += (size_t)GC*HC/2;
    float* cBh  = W + o; o += (size_t)GC*HC/2;
    float* cBl  = W + o; o += (size_t)GC*HC/2;
    float* f1h  = W + o; o += (size_t)HWID*1024/2;    // ff1W pairs
    float* f1l  = W + o; o += (size_t)HWID*1024/2;

    u16* Xh = (u16*)XhF;  u16* Xl = (u16*)XlF;
    u16* Eh = (u16*)EhF;  u16* El = (u16*)ElF;
    // char state aliases inside ENC-hi region (disjoint in time, exactly fills it)
    u16*   Hh = (u16*)EhF;
    u16*   Hl = (u16*)(EhF + (size_t)NSEQ*HC);
    float* Cc = EhF + (size_t)2*NSEQ*HC;
    float* HFF = AXCF;                  // ff1 hidden (spans AXCF+AXCB)
    float* LOG = XhF;                   // logits, after X dead
    int*   BP  = (int*)(XhF + (size_t)NSB*TT);

    dim3 blk(256);

    // ---- precomputes -------------------------------------------------------
    char_pmat<<<(2*128*GC+255)/256, blk, 0, stream>>>(chemb, cWihF, cWihB,
                                                      cBihF, cBhhF, cBihB, cBhhB, PF, PB);
    x_fill_pair<<<((size_t)NSB*320+255)/256, blk, 0, stream>>>(word_in, cap_in, wemb, cemb, Xh, Xl);
    bias_sum<<<(GW+255)/256, blk, 0, stream>>>(wBihF, wBhhF, wBihB, wBhhB, BSF, BSB, GW);
    pad_w_split<<<(2*GW*DDP+255)/256, blk, 0, stream>>>(wWihF, wWihB,
                                                        (u16*)WFh,(u16*)WFl,(u16*)WBh,(u16*)WBl);
    split_pair<<<(GC*HC+255)/256, blk, 0, stream>>>(cWhhF, (u16*)cFh, (u16*)cFl, GC*HC);
    split_pair<<<(GC*HC+255)/256, blk, 0, stream>>>(cWhhB, (u16*)cBh, (u16*)cBl, GC*HC);
    split_pair<<<(HWID*1024+255)/256, blk, 0, stream>>>(ff1W, (u16*)f1h, (u16*)f1l, HWID*1024);

    // ---- char BiLSTM (MFMA) ------------------------------------------------
    zero_f<<<((size_t)NSB*1024/2+255)/256, blk, 0, stream>>>(EhF, NSB*1024/2); // h/c init
    for (int k=0;k<WLEN;k++){
        char_step_mfma<<<1024, blk, 0, stream>>>((u16*)cFh,(u16*)cFl,(u16*)cBh,(u16*)cBl,
                                                 PF, PB, char_in, Hh, Hl, Cc, Xh, Xl, k);
    }

    // ---- word BiLSTM, chunked MFMA input projection ------------------------
    zero_f<<<(2*BATCH*HWID+255)/256, blk, 0, stream>>>(HWb, 2*BATCH*HWID);
    zero_f<<<(2*BATCH*HWID+255)/256, blk, 0, stream>>>(CW,  2*BATCH*HWID);
    dim3 gax(CROWS/128, GW/128);   // (16, 16)
    for (int j=0;j<S_LEN/CHUNK;j++){
        int sbf = j*CHUNK;
        int sbb = (S_LEN-CHUNK) - j*CHUNK;
        gemm_mfma<<<gax, blk, 0, stream>>>(Xh + (size_t)sbf*BATCH*DDP, Xl + (size_t)sbf*BATCH*DDP, DDP,
                                           (u16*)WFh, (u16*)WFl, DDP,
                                           AXCF, GW, DDP, BSF, 0);
        gemm_mfma<<<gax, blk, 0, stream>>>(Xh + (size_t)sbb*BATCH*DDP, Xl + (size_t)sbb*BATCH*DDP, DDP,
                                           (u16*)WBh, (u16*)WBl, DDP,
                                           AXCB, GW, DDP, BSB, 0);
        for (int t=0;t<CHUNK;t++){
            int ss = j*CHUNK + t;
            int par = ss & 1;
            word_step<<<256, blk, 0, stream>>>(AXCF, AXCB, wWhhF, wWhhB,
                HWb + (size_t)par*2*BATCH*HWID,
                HWb + (size_t)(1-par)*2*BATCH*HWID,
                CW, Eh, El, ss, sbf, sbb);
        }
    }

    // ---- feed-forward head -------------------------------------------------
    dim3 g1(NSB/128, HWID/128);    // (128, 4)
    gemm_mfma<<<g1, blk, 0, stream>>>(Eh, El, 1024, (u16*)f1h, (u16*)f1l, 1024,
                                      HFF, HWID, 1024, ff1b, 1);
    dim3 g2(NSB/128, 1);
    gemm128<<<g2, blk, 0, stream>>>(HFF, HWID, ff2W, HWID, LOG, TT,
                                    NSB, TT, HWID, ff2b, 0);

    // ---- CRF loss + Viterbi ------------------------------------------------
    zero_f<<<1, dim3(64), 0, stream>>>(out, 1);
    crf_loss<<<BATCH, dim3(64), 0, stream>>>(LOG, tag_in, trans, startT, endT, out);
    viterbi_k<<<BATCH, dim3(64), 0, stream>>>(LOG, trans, startT, endT, BP, out+1);
}